// Round 3
// baseline (392.732 us; speedup 1.0000x reference)
//
#include <hip/hip_runtime.h>

// BayesianLayer: out[b,o] = sum_i x[b,i]*(eps[b,i,o]*softplus(ro[i,o]) + mu[i,o])
//                          + eps_bias[b,o]*softplus(ro_bias[o]) + mu_bias[o]
// B=64, IN=1024, OUT=1024, fp32. Memory-bound on eps (256 MB, read-once).
//
// Deterministic 3-kernel pipeline (no atomics, no output memset):
//   A: sig[i,o]    = softplus(ro[i,o])                  -> ws[0 .. 1M)
//   B: part[b,c,o] = sum_{i in chunk c} x*(eps*sig+mu)  -> ws[1M .. 3M)
//   C: out[b,o]    = sum_c part + eps_bias*softplus(ro_bias) + mu_bias
//
// R3 changes vs R2 (main kernel):
//  - dropped nontemporal hint on eps loads (fill kernel proves plain
//    accesses stream at 6.5 TB/s; nt changes L2 allocation policy)
//  - loop order b OUTER, il INNER, unroll 8: each wave sweeps a contiguous
//    128 KB eps region with 8 independent 1 KB loads in flight, instead of
//    hopping between four 4 MB-apart regions every iteration

#define BB   64
#define INN  1024
#define OUTT 1024
#define B_T  4               // batch rows per main block
#define ICH  32              // split-K chunks over IN
#define I_C  (INN / ICH)     // 32 i's per main block

typedef float f4 __attribute__((ext_vector_type(4)));

__device__ __forceinline__ float softplus_f(float v) {
    return fmaxf(v, 0.0f) + log1pf(__expf(-fabsf(v)));
}

// ---- kernel A: sig = softplus(ro), 1M elements as 256K float4 ----
__global__ __launch_bounds__(256) void bayes_sig(
    const float* __restrict__ ro, float* __restrict__ sig)
{
    const int g = blockIdx.x * 256 + threadIdx.x;      // float4 index
    const f4 r = *(const f4*)(ro + (size_t)g * 4);
    f4 s;
    s.x = softplus_f(r.x); s.y = softplus_f(r.y);
    s.z = softplus_f(r.z); s.w = softplus_f(r.w);
    *(f4*)(sig + (size_t)g * 4) = s;
}

// ---- kernel B: split-K partials ----
__global__ __launch_bounds__(256) void bayes_main(
    const float* __restrict__ x,        // [B, IN]
    const float* __restrict__ mu,       // [IN, OUT]
    const float* __restrict__ sig,      // [IN, OUT] (precomputed softplus)
    const float* __restrict__ eps,      // [B, IN, OUT]
    float* __restrict__ part)           // [B, ICH, OUT]
{
    __shared__ float xs[B_T][I_C];

    const int t  = threadIdx.x;
    const int o  = t << 2;
    const int c  = blockIdx.x;          // chunk
    const int b0 = blockIdx.y * B_T;
    const int i0 = c * I_C;

    if (t < B_T * I_C) {
        const int b  = t / I_C;
        const int il = t % I_C;
        xs[b][il] = x[(b0 + b) * INN + i0 + il];
    }
    __syncthreads();

    const float* sig_p = sig + (size_t)i0 * OUTT + o;
    const float* mu_p  = mu  + (size_t)i0 * OUTT + o;

#pragma unroll
    for (int b = 0; b < B_T; ++b) {
        const float* eps_p = eps + ((size_t)(b0 + b) * INN + i0) * OUTT + o;
        f4 acc = (f4)0.0f;
#pragma unroll 8
        for (int il = 0; il < I_C; ++il) {
            const f4 e   = *(const f4*)(eps_p + (size_t)il * OUTT);
            const f4 sg4 = *(const f4*)(sig_p + (size_t)il * OUTT);
            const f4 mu4 = *(const f4*)(mu_p  + (size_t)il * OUTT);
            const float xb = xs[b][il];
            acc.x = fmaf(xb, fmaf(e.x, sg4.x, mu4.x), acc.x);
            acc.y = fmaf(xb, fmaf(e.y, sg4.y, mu4.y), acc.y);
            acc.z = fmaf(xb, fmaf(e.z, sg4.z, mu4.z), acc.z);
            acc.w = fmaf(xb, fmaf(e.w, sg4.w, mu4.w), acc.w);
        }
        *(f4*)(part + ((size_t)(b0 + b) * ICH + c) * OUTT + o) = acc;
    }
}

// ---- kernel C: reduce 32 partials + bias ----
__global__ __launch_bounds__(256) void bayes_reduce(
    const float* __restrict__ part,     // [B, ICH, OUT]
    const float* __restrict__ mu_bias,  // [OUT]
    const float* __restrict__ ro_bias,  // [OUT]
    const float* __restrict__ eps_bias, // [B, OUT]
    float* __restrict__ out)            // [B, OUT]
{
    const int g  = blockIdx.x * 256 + threadIdx.x;   // float4 index over [B*OUT/4]
    const int b  = g >> 8;                           // 256 float4 per row
    const int o  = (g & 255) << 2;

    f4 s = (f4)0.0f;
#pragma unroll
    for (int c = 0; c < ICH; ++c) {
        const f4 p = *(const f4*)(part + ((size_t)b * ICH + c) * OUTT + o);
        s.x += p.x; s.y += p.y; s.z += p.z; s.w += p.w;
    }

    const f4 rb = *(const f4*)(ro_bias + o);
    const f4 mb = *(const f4*)(mu_bias + o);
    const f4 eb = *(const f4*)(eps_bias + (size_t)b * OUTT + o);
    s.x += fmaf(eb.x, softplus_f(rb.x), mb.x);
    s.y += fmaf(eb.y, softplus_f(rb.y), mb.y);
    s.z += fmaf(eb.z, softplus_f(rb.z), mb.z);
    s.w += fmaf(eb.w, softplus_f(rb.w), mb.w);

    *(f4*)(out + (size_t)g * 4) = s;
}

// ---- fallback (ws too small): single deterministic kernel, no scratch ----
__global__ __launch_bounds__(256) void bayes_mono(
    const float* __restrict__ x, const float* __restrict__ mu,
    const float* __restrict__ ro, const float* __restrict__ mu_bias,
    const float* __restrict__ ro_bias, const float* __restrict__ eps,
    const float* __restrict__ eps_bias, float* __restrict__ out)
{
    const int t = threadIdx.x;
    const int o = t << 2;
    const int b = blockIdx.x;

    f4 acc = (f4)0.0f;
    for (int i = 0; i < INN; ++i) {
        const float xb = x[b * INN + i];
        const f4 r4 = *(const f4*)(ro + (size_t)i * OUTT + o);
        const f4 m4 = *(const f4*)(mu + (size_t)i * OUTT + o);
        const f4 e  = *(const f4*)(eps + ((size_t)b * INN + i) * OUTT + o);
        acc.x = fmaf(xb, fmaf(e.x, softplus_f(r4.x), m4.x), acc.x);
        acc.y = fmaf(xb, fmaf(e.y, softplus_f(r4.y), m4.y), acc.y);
        acc.z = fmaf(xb, fmaf(e.z, softplus_f(r4.z), m4.z), acc.z);
        acc.w = fmaf(xb, fmaf(e.w, softplus_f(r4.w), m4.w), acc.w);
    }
    const f4 rb = *(const f4*)(ro_bias + o);
    const f4 mb = *(const f4*)(mu_bias + o);
    const f4 eb = *(const f4*)(eps_bias + (size_t)b * OUTT + o);
    acc.x += fmaf(eb.x, softplus_f(rb.x), mb.x);
    acc.y += fmaf(eb.y, softplus_f(rb.y), mb.y);
    acc.z += fmaf(eb.z, softplus_f(rb.z), mb.z);
    acc.w += fmaf(eb.w, softplus_f(rb.w), mb.w);
    *(f4*)(out + (size_t)b * OUTT + o) = acc;
}

extern "C" void kernel_launch(void* const* d_in, const int* in_sizes, int n_in,
                              void* d_out, int out_size, void* d_ws, size_t ws_size,
                              hipStream_t stream) {
    const float* x        = (const float*)d_in[0];
    const float* mu       = (const float*)d_in[1];
    const float* ro       = (const float*)d_in[2];
    const float* mu_bias  = (const float*)d_in[3];
    const float* ro_bias  = (const float*)d_in[4];
    const float* eps      = (const float*)d_in[5];
    const float* eps_bias = (const float*)d_in[6];
    float* out = (float*)d_out;

    const size_t sig_elems  = (size_t)INN * OUTT;        // 1M floats
    const size_t part_elems = (size_t)BB * ICH * OUTT;   // 2M floats
    const size_t need = (sig_elems + part_elems) * sizeof(float);  // 12 MB

    if (ws_size >= need) {
        float* sig  = (float*)d_ws;
        float* part = sig + sig_elems;

        bayes_sig<<<sig_elems / 1024, 256, 0, stream>>>(ro, sig);
        dim3 grid(ICH, BB / B_T);   // 32 x 16 = 512 blocks, 2 blocks/CU
        bayes_main<<<grid, 256, 0, stream>>>(x, mu, sig, eps, part);
        bayes_reduce<<<(BB * OUTT / 4) / 256, 256, 0, stream>>>(
            part, mu_bias, ro_bias, eps_bias, out);
    } else {
        bayes_mono<<<BB, 256, 0, stream>>>(x, mu, ro, mu_bias, ro_bias,
                                           eps, eps_bias, out);
    }
}

// Round 4
// 389.724 us; speedup vs baseline: 1.0077x; 1.0077x over previous
//
#include <hip/hip_runtime.h>

// BayesianLayer: out[b,o] = sum_i x[b,i]*(eps[b,i,o]*softplus(ro[i,o]) + mu[i,o])
//                          + eps_bias[b,o]*softplus(ro_bias[o]) + mu_bias[o]
// B=64, IN=1024, OUT=1024, fp32. Memory-bound on eps (256 MB, read-once).
//
// Deterministic 3-kernel pipeline (no atomics, no output memset):
//   A: sig[i,o]    = softplus(ro[i,o])                  -> ws
//   B: part[b,c,o] = sum_{i in chunk c} x*(eps*sig+mu)  -> ws
//   C: out[b,o]    = sum_c part + eps_bias*softplus(ro_bias) + mu_bias
//
// R4: main kernel made maximally fill-like (the 1-GiB harness fill streams
// at 6.5 TB/s with 8 VGPRs — mimic it):
//  - B_T=1: one block = ONE contiguous 256 KB eps run (64 i x 4 KB)
//  - ICH=16, grid 1024 blocks = 4 blocks/CU = 16 waves/CU (2x R2 occupancy)
//  - no LDS, no syncthreads; x[b,i] is block-uniform -> scalar loads
//  - same-chunk blocks are 16 apart in linear ID -> same XCD under
//    round-robin dispatch -> sig/mu chunk stays in that XCD's L2

#define BB   64
#define INN  1024
#define OUTT 1024
#define ICH  16              // split-K chunks over IN
#define I_C  (INN / ICH)     // 64 i's per main block

typedef float f4 __attribute__((ext_vector_type(4)));

__device__ __forceinline__ float softplus_f(float v) {
    return fmaxf(v, 0.0f) + log1pf(__expf(-fabsf(v)));
}

// ---- kernel A: sig = softplus(ro), 1M elements as 256K float4 ----
__global__ __launch_bounds__(256) void bayes_sig(
    const float* __restrict__ ro, float* __restrict__ sig)
{
    const int g = blockIdx.x * 256 + threadIdx.x;      // float4 index
    const f4 r = *(const f4*)(ro + (size_t)g * 4);
    f4 s;
    s.x = softplus_f(r.x); s.y = softplus_f(r.y);
    s.z = softplus_f(r.z); s.w = softplus_f(r.w);
    *(f4*)(sig + (size_t)g * 4) = s;
}

// ---- kernel B: split-K partials, one (b, chunk) per block ----
__global__ __launch_bounds__(256) void bayes_main(
    const float* __restrict__ x,        // [B, IN]
    const float* __restrict__ mu,       // [IN, OUT]
    const float* __restrict__ sig,      // [IN, OUT] (precomputed softplus)
    const float* __restrict__ eps,      // [B, IN, OUT]
    float* __restrict__ part)           // [B, ICH, OUT]
{
    const int t  = threadIdx.x;
    const int o  = t << 2;              // 4 consecutive outputs per thread
    const int c  = blockIdx.x;          // chunk
    const int b  = blockIdx.y;          // batch row
    const int i0 = c * I_C;

    const float* __restrict__ xp    = x   + (size_t)b * INN + i0;   // uniform
    const float* __restrict__ eps_p = eps + ((size_t)b * INN + i0) * OUTT + o;
    const float* __restrict__ sig_p = sig + (size_t)i0 * OUTT + o;
    const float* __restrict__ mu_p  = mu  + (size_t)i0 * OUTT + o;

    f4 acc = (f4)0.0f;
#pragma unroll 8
    for (int il = 0; il < I_C; ++il) {
        const float xb  = xp[il];                         // scalar (uniform) load
        const f4    e   = *(const f4*)(eps_p + (size_t)il * OUTT);
        const f4    sg4 = *(const f4*)(sig_p + (size_t)il * OUTT);
        const f4    mu4 = *(const f4*)(mu_p  + (size_t)il * OUTT);
        acc.x = fmaf(xb, fmaf(e.x, sg4.x, mu4.x), acc.x);
        acc.y = fmaf(xb, fmaf(e.y, sg4.y, mu4.y), acc.y);
        acc.z = fmaf(xb, fmaf(e.z, sg4.z, mu4.z), acc.z);
        acc.w = fmaf(xb, fmaf(e.w, sg4.w, mu4.w), acc.w);
    }

    *(f4*)(part + ((size_t)b * ICH + c) * OUTT + o) = acc;
}

// ---- kernel C: reduce ICH partials + bias ----
__global__ __launch_bounds__(256) void bayes_reduce(
    const float* __restrict__ part,     // [B, ICH, OUT]
    const float* __restrict__ mu_bias,  // [OUT]
    const float* __restrict__ ro_bias,  // [OUT]
    const float* __restrict__ eps_bias, // [B, OUT]
    float* __restrict__ out)            // [B, OUT]
{
    const int g  = blockIdx.x * 256 + threadIdx.x;   // float4 index over [B*OUT/4]
    const int b  = g >> 8;                           // 256 float4 per row
    const int o  = (g & 255) << 2;

    f4 s = (f4)0.0f;
#pragma unroll
    for (int c = 0; c < ICH; ++c) {
        const f4 p = *(const f4*)(part + ((size_t)b * ICH + c) * OUTT + o);
        s.x += p.x; s.y += p.y; s.z += p.z; s.w += p.w;
    }

    const f4 rb = *(const f4*)(ro_bias + o);
    const f4 mb = *(const f4*)(mu_bias + o);
    const f4 eb = *(const f4*)(eps_bias + (size_t)b * OUTT + o);
    s.x += fmaf(eb.x, softplus_f(rb.x), mb.x);
    s.y += fmaf(eb.y, softplus_f(rb.y), mb.y);
    s.z += fmaf(eb.z, softplus_f(rb.z), mb.z);
    s.w += fmaf(eb.w, softplus_f(rb.w), mb.w);

    *(f4*)(out + (size_t)g * 4) = s;
}

// ---- fallback (ws too small): single deterministic kernel, no scratch ----
__global__ __launch_bounds__(256) void bayes_mono(
    const float* __restrict__ x, const float* __restrict__ mu,
    const float* __restrict__ ro, const float* __restrict__ mu_bias,
    const float* __restrict__ ro_bias, const float* __restrict__ eps,
    const float* __restrict__ eps_bias, float* __restrict__ out)
{
    const int t = threadIdx.x;
    const int o = t << 2;
    const int b = blockIdx.x;

    f4 acc = (f4)0.0f;
    for (int i = 0; i < INN; ++i) {
        const float xb = x[b * INN + i];
        const f4 r4 = *(const f4*)(ro + (size_t)i * OUTT + o);
        const f4 m4 = *(const f4*)(mu + (size_t)i * OUTT + o);
        const f4 e  = *(const f4*)(eps + ((size_t)b * INN + i) * OUTT + o);
        acc.x = fmaf(xb, fmaf(e.x, softplus_f(r4.x), m4.x), acc.x);
        acc.y = fmaf(xb, fmaf(e.y, softplus_f(r4.y), m4.y), acc.y);
        acc.z = fmaf(xb, fmaf(e.z, softplus_f(r4.z), m4.z), acc.z);
        acc.w = fmaf(xb, fmaf(e.w, softplus_f(r4.w), m4.w), acc.w);
    }
    const f4 rb = *(const f4*)(ro_bias + o);
    const f4 mb = *(const f4*)(mu_bias + o);
    const f4 eb = *(const f4*)(eps_bias + (size_t)b * OUTT + o);
    acc.x += fmaf(eb.x, softplus_f(rb.x), mb.x);
    acc.y += fmaf(eb.y, softplus_f(rb.y), mb.y);
    acc.z += fmaf(eb.z, softplus_f(rb.z), mb.z);
    acc.w += fmaf(eb.w, softplus_f(rb.w), mb.w);
    *(f4*)(out + (size_t)b * OUTT + o) = acc;
}

extern "C" void kernel_launch(void* const* d_in, const int* in_sizes, int n_in,
                              void* d_out, int out_size, void* d_ws, size_t ws_size,
                              hipStream_t stream) {
    const float* x        = (const float*)d_in[0];
    const float* mu       = (const float*)d_in[1];
    const float* ro       = (const float*)d_in[2];
    const float* mu_bias  = (const float*)d_in[3];
    const float* ro_bias  = (const float*)d_in[4];
    const float* eps      = (const float*)d_in[5];
    const float* eps_bias = (const float*)d_in[6];
    float* out = (float*)d_out;

    const size_t sig_elems  = (size_t)INN * OUTT;        // 1M floats
    const size_t part_elems = (size_t)BB * ICH * OUTT;   // 1M floats
    const size_t need = (sig_elems + part_elems) * sizeof(float);  // 8 MB

    if (ws_size >= need) {
        float* sig  = (float*)d_ws;
        float* part = sig + sig_elems;

        bayes_sig<<<sig_elems / 1024, 256, 0, stream>>>(ro, sig);
        dim3 grid(ICH, BB);   // 16 x 64 = 1024 blocks, 4 blocks/CU
        bayes_main<<<grid, 256, 0, stream>>>(x, mu, sig, eps, part);
        bayes_reduce<<<(BB * OUTT / 4) / 256, 256, 0, stream>>>(
            part, mu_bias, ro_bias, eps_bias, out);
    } else {
        bayes_mono<<<BB, 256, 0, stream>>>(x, mu, ro, mu_bias, ro_bias,
                                           eps, eps_bias, out);
    }
}

// Round 5
// 389.124 us; speedup vs baseline: 1.0093x; 1.0015x over previous
//
#include <hip/hip_runtime.h>

// BayesianLayer: out[b,o] = sum_i x[b,i]*(eps[b,i,o]*softplus(ro[i,o]) + mu[i,o])
//                          + eps_bias[b,o]*softplus(ro_bias[o]) + mu_bias[o]
// B=64, IN=1024, OUT=1024, fp32. Memory-bound on eps (256 MB, read-once).
//
// R5 = R2's winning structure (B_T=4, b-inner reuse of sig/mu) with:
//  - ICH 32->64 (I_C=16): grid 64x16 = 1024 blocks = 4 blocks/CU = 16 waves/CU
//    (2x R2 occupancy, same access pattern)
//  - kernel A deleted: softplus(ro) computed inline once per (i,o) and
//    amortized over the 4 b-rows (saves 8 MB traffic + a launch + a gap)
//  - chunk c -> XCD c%8 under round-robin (linear id = c + 64*bg), so each
//    chunk's 128 KB ro+mu slice stays L2-resident for its 16 reader blocks
// Deterministic: plain stores to part, separate reduce kernel. No atomics,
// no output memset (graph-replay safe).

#define BB   64
#define INN  1024
#define OUTT 1024
#define B_T  4               // batch rows per main block (ro/mu/softplus reuse)
#define ICH  64              // split-K chunks over IN
#define I_C  (INN / ICH)     // 16 i's per main block

typedef float f4 __attribute__((ext_vector_type(4)));

__device__ __forceinline__ float softplus_f(float v) {
    return fmaxf(v, 0.0f) + log1pf(__expf(-fabsf(v)));
}

// ---- main kernel: split-K partials ----
__global__ __launch_bounds__(256) void bayes_main(
    const float* __restrict__ x,        // [B, IN]
    const float* __restrict__ mu,       // [IN, OUT]
    const float* __restrict__ ro,       // [IN, OUT]
    const float* __restrict__ eps,      // [B, IN, OUT]
    float* __restrict__ part)           // [B, ICH, OUT]
{
    __shared__ float xs[B_T][I_C];

    const int t  = threadIdx.x;
    const int o  = t << 2;
    const int c  = blockIdx.x;          // chunk
    const int b0 = blockIdx.y * B_T;
    const int i0 = c * I_C;

    if (t < B_T * I_C) {                // 64 threads stage x tile
        const int b  = t / I_C;
        const int il = t % I_C;
        xs[b][il] = x[(b0 + b) * INN + i0 + il];
    }
    __syncthreads();

    f4 acc[B_T];
#pragma unroll
    for (int b = 0; b < B_T; ++b) acc[b] = (f4)0.0f;

#pragma unroll 4
    for (int il = 0; il < I_C; ++il) {
        const int i = i0 + il;
        const f4 ro4 = *(const f4*)(ro + (size_t)i * OUTT + o);
        const f4 mu4 = *(const f4*)(mu + (size_t)i * OUTT + o);
        f4 sg4;
        sg4.x = softplus_f(ro4.x);
        sg4.y = softplus_f(ro4.y);
        sg4.z = softplus_f(ro4.z);
        sg4.w = softplus_f(ro4.w);
#pragma unroll
        for (int b = 0; b < B_T; ++b) {
            const float xb = xs[b][il];
            const f4 e = *(const f4*)(eps + ((size_t)(b0 + b) * INN + i) * OUTT + o);
            acc[b].x = fmaf(xb, fmaf(e.x, sg4.x, mu4.x), acc[b].x);
            acc[b].y = fmaf(xb, fmaf(e.y, sg4.y, mu4.y), acc[b].y);
            acc[b].z = fmaf(xb, fmaf(e.z, sg4.z, mu4.z), acc[b].z);
            acc[b].w = fmaf(xb, fmaf(e.w, sg4.w, mu4.w), acc[b].w);
        }
    }

#pragma unroll
    for (int b = 0; b < B_T; ++b) {
        *(f4*)(part + ((size_t)(b0 + b) * ICH + c) * OUTT + o) = acc[b];
    }
}

// ---- reduce kernel: sum ICH partials + bias ----
__global__ __launch_bounds__(256) void bayes_reduce(
    const float* __restrict__ part,     // [B, ICH, OUT]
    const float* __restrict__ mu_bias,  // [OUT]
    const float* __restrict__ ro_bias,  // [OUT]
    const float* __restrict__ eps_bias, // [B, OUT]
    float* __restrict__ out)            // [B, OUT]
{
    const int g  = blockIdx.x * 256 + threadIdx.x;   // float4 index over [B*OUT/4]
    const int b  = g >> 8;                           // 256 float4 per row
    const int o  = (g & 255) << 2;

    f4 s = (f4)0.0f;
#pragma unroll 8
    for (int c = 0; c < ICH; ++c) {
        const f4 p = *(const f4*)(part + ((size_t)b * ICH + c) * OUTT + o);
        s.x += p.x; s.y += p.y; s.z += p.z; s.w += p.w;
    }

    const f4 rb = *(const f4*)(ro_bias + o);
    const f4 mb = *(const f4*)(mu_bias + o);
    const f4 eb = *(const f4*)(eps_bias + (size_t)b * OUTT + o);
    s.x += fmaf(eb.x, softplus_f(rb.x), mb.x);
    s.y += fmaf(eb.y, softplus_f(rb.y), mb.y);
    s.z += fmaf(eb.z, softplus_f(rb.z), mb.z);
    s.w += fmaf(eb.w, softplus_f(rb.w), mb.w);

    *(f4*)(out + (size_t)g * 4) = s;
}

// ---- fallback (ws too small): single deterministic kernel, no scratch ----
__global__ __launch_bounds__(256) void bayes_mono(
    const float* __restrict__ x, const float* __restrict__ mu,
    const float* __restrict__ ro, const float* __restrict__ mu_bias,
    const float* __restrict__ ro_bias, const float* __restrict__ eps,
    const float* __restrict__ eps_bias, float* __restrict__ out)
{
    const int t = threadIdx.x;
    const int o = t << 2;
    const int b = blockIdx.x;

    f4 acc = (f4)0.0f;
    for (int i = 0; i < INN; ++i) {
        const float xb = x[b * INN + i];
        const f4 r4 = *(const f4*)(ro + (size_t)i * OUTT + o);
        const f4 m4 = *(const f4*)(mu + (size_t)i * OUTT + o);
        const f4 e  = *(const f4*)(eps + ((size_t)b * INN + i) * OUTT + o);
        acc.x = fmaf(xb, fmaf(e.x, softplus_f(r4.x), m4.x), acc.x);
        acc.y = fmaf(xb, fmaf(e.y, softplus_f(r4.y), m4.y), acc.y);
        acc.z = fmaf(xb, fmaf(e.z, softplus_f(r4.z), m4.z), acc.z);
        acc.w = fmaf(xb, fmaf(e.w, softplus_f(r4.w), m4.w), acc.w);
    }
    const f4 rb = *(const f4*)(ro_bias + o);
    const f4 mb = *(const f4*)(mu_bias + o);
    const f4 eb = *(const f4*)(eps_bias + (size_t)b * OUTT + o);
    acc.x += fmaf(eb.x, softplus_f(rb.x), mb.x);
    acc.y += fmaf(eb.y, softplus_f(rb.y), mb.y);
    acc.z += fmaf(eb.z, softplus_f(rb.z), mb.z);
    acc.w += fmaf(eb.w, softplus_f(rb.w), mb.w);
    *(f4*)(out + (size_t)b * OUTT + o) = acc;
}

extern "C" void kernel_launch(void* const* d_in, const int* in_sizes, int n_in,
                              void* d_out, int out_size, void* d_ws, size_t ws_size,
                              hipStream_t stream) {
    const float* x        = (const float*)d_in[0];
    const float* mu       = (const float*)d_in[1];
    const float* ro       = (const float*)d_in[2];
    const float* mu_bias  = (const float*)d_in[3];
    const float* ro_bias  = (const float*)d_in[4];
    const float* eps      = (const float*)d_in[5];
    const float* eps_bias = (const float*)d_in[6];
    float* out = (float*)d_out;

    const size_t part_elems = (size_t)BB * ICH * OUTT;   // 4M floats = 16 MB
    const size_t need = part_elems * sizeof(float);

    if (ws_size >= need) {
        float* part = (float*)d_ws;

        dim3 grid(ICH, BB / B_T);   // 64 x 16 = 1024 blocks, 4 blocks/CU
        bayes_main<<<grid, 256, 0, stream>>>(x, mu, ro, eps, part);
        bayes_reduce<<<(BB * OUTT / 4) / 256, 256, 0, stream>>>(
            part, mu_bias, ro_bias, eps_bias, out);
    } else {
        bayes_mono<<<BB, 256, 0, stream>>>(x, mu, ro, mu_bias, ro_bias,
                                           eps, eps_bias, out);
    }
}

// Round 6
// 385.795 us; speedup vs baseline: 1.0180x; 1.0086x over previous
//
#include <hip/hip_runtime.h>

// BayesianLayer: out[b,o] = sum_i x[b,i]*(eps[b,i,o]*softplus(ro[i,o]) + mu[i,o])
//                          + eps_bias[b,o]*softplus(ro_bias[o]) + mu_bias[o]
// B=64, IN=1024, OUT=1024, fp32. Memory-bound on eps (256 MB, read-once).
//
// R6 = R5 structure + RESTORED __builtin_nontemporal_load on eps (the one
// variable R2 had and R3-R5 lost; R2=368.9 is still the best measurement).
// Mechanism: eps is strictly read-once -> nt bypasses L2 allocation, keeping
// the 32 MB L2 for mu/ro (16x reuse per chunk) and the part write-backs.
// Everything else identical to R5 (single-variable experiment):
//  - B_T=4, b-inner reuse of inline-softplus(ro)/mu
//  - ICH=64: grid 64x16 = 1024 blocks = 4 blocks/CU = 16 waves/CU
//  - deterministic: plain part stores + separate reduce, no atomics/memset

#define BB   64
#define INN  1024
#define OUTT 1024
#define B_T  4               // batch rows per main block (ro/mu/softplus reuse)
#define ICH  64              // split-K chunks over IN
#define I_C  (INN / ICH)     // 16 i's per main block

typedef float f4 __attribute__((ext_vector_type(4)));

__device__ __forceinline__ float softplus_f(float v) {
    return fmaxf(v, 0.0f) + log1pf(__expf(-fabsf(v)));
}

// ---- main kernel: split-K partials ----
__global__ __launch_bounds__(256) void bayes_main(
    const float* __restrict__ x,        // [B, IN]
    const float* __restrict__ mu,       // [IN, OUT]
    const float* __restrict__ ro,       // [IN, OUT]
    const float* __restrict__ eps,      // [B, IN, OUT]
    float* __restrict__ part)           // [B, ICH, OUT]
{
    __shared__ float xs[B_T][I_C];

    const int t  = threadIdx.x;
    const int o  = t << 2;
    const int c  = blockIdx.x;          // chunk
    const int b0 = blockIdx.y * B_T;
    const int i0 = c * I_C;

    if (t < B_T * I_C) {                // 64 threads stage x tile
        const int b  = t / I_C;
        const int il = t % I_C;
        xs[b][il] = x[(b0 + b) * INN + i0 + il];
    }
    __syncthreads();

    f4 acc[B_T];
#pragma unroll
    for (int b = 0; b < B_T; ++b) acc[b] = (f4)0.0f;

#pragma unroll 4
    for (int il = 0; il < I_C; ++il) {
        const int i = i0 + il;
        const f4 ro4 = *(const f4*)(ro + (size_t)i * OUTT + o);
        const f4 mu4 = *(const f4*)(mu + (size_t)i * OUTT + o);
        f4 sg4;
        sg4.x = softplus_f(ro4.x);
        sg4.y = softplus_f(ro4.y);
        sg4.z = softplus_f(ro4.z);
        sg4.w = softplus_f(ro4.w);
#pragma unroll
        for (int b = 0; b < B_T; ++b) {
            const float xb = xs[b][il];
            const f4 e = __builtin_nontemporal_load(
                (const f4*)(eps + ((size_t)(b0 + b) * INN + i) * OUTT + o));
            acc[b].x = fmaf(xb, fmaf(e.x, sg4.x, mu4.x), acc[b].x);
            acc[b].y = fmaf(xb, fmaf(e.y, sg4.y, mu4.y), acc[b].y);
            acc[b].z = fmaf(xb, fmaf(e.z, sg4.z, mu4.z), acc[b].z);
            acc[b].w = fmaf(xb, fmaf(e.w, sg4.w, mu4.w), acc[b].w);
        }
    }

#pragma unroll
    for (int b = 0; b < B_T; ++b) {
        *(f4*)(part + ((size_t)(b0 + b) * ICH + c) * OUTT + o) = acc[b];
    }
}

// ---- reduce kernel: sum ICH partials + bias ----
__global__ __launch_bounds__(256) void bayes_reduce(
    const float* __restrict__ part,     // [B, ICH, OUT]
    const float* __restrict__ mu_bias,  // [OUT]
    const float* __restrict__ ro_bias,  // [OUT]
    const float* __restrict__ eps_bias, // [B, OUT]
    float* __restrict__ out)            // [B, OUT]
{
    const int g  = blockIdx.x * 256 + threadIdx.x;   // float4 index over [B*OUT/4]
    const int b  = g >> 8;                           // 256 float4 per row
    const int o  = (g & 255) << 2;

    f4 s = (f4)0.0f;
#pragma unroll 8
    for (int c = 0; c < ICH; ++c) {
        const f4 p = *(const f4*)(part + ((size_t)b * ICH + c) * OUTT + o);
        s.x += p.x; s.y += p.y; s.z += p.z; s.w += p.w;
    }

    const f4 rb = *(const f4*)(ro_bias + o);
    const f4 mb = *(const f4*)(mu_bias + o);
    const f4 eb = *(const f4*)(eps_bias + (size_t)b * OUTT + o);
    s.x += fmaf(eb.x, softplus_f(rb.x), mb.x);
    s.y += fmaf(eb.y, softplus_f(rb.y), mb.y);
    s.z += fmaf(eb.z, softplus_f(rb.z), mb.z);
    s.w += fmaf(eb.w, softplus_f(rb.w), mb.w);

    *(f4*)(out + (size_t)g * 4) = s;
}

// ---- fallback (ws too small): single deterministic kernel, no scratch ----
__global__ __launch_bounds__(256) void bayes_mono(
    const float* __restrict__ x, const float* __restrict__ mu,
    const float* __restrict__ ro, const float* __restrict__ mu_bias,
    const float* __restrict__ ro_bias, const float* __restrict__ eps,
    const float* __restrict__ eps_bias, float* __restrict__ out)
{
    const int t = threadIdx.x;
    const int o = t << 2;
    const int b = blockIdx.x;

    f4 acc = (f4)0.0f;
    for (int i = 0; i < INN; ++i) {
        const float xb = x[b * INN + i];
        const f4 r4 = *(const f4*)(ro + (size_t)i * OUTT + o);
        const f4 m4 = *(const f4*)(mu + (size_t)i * OUTT + o);
        const f4 e  = *(const f4*)(eps + ((size_t)b * INN + i) * OUTT + o);
        acc.x = fmaf(xb, fmaf(e.x, softplus_f(r4.x), m4.x), acc.x);
        acc.y = fmaf(xb, fmaf(e.y, softplus_f(r4.y), m4.y), acc.y);
        acc.z = fmaf(xb, fmaf(e.z, softplus_f(r4.z), m4.z), acc.z);
        acc.w = fmaf(xb, fmaf(e.w, softplus_f(r4.w), m4.w), acc.w);
    }
    const f4 rb = *(const f4*)(ro_bias + o);
    const f4 mb = *(const f4*)(mu_bias + o);
    const f4 eb = *(const f4*)(eps_bias + (size_t)b * OUTT + o);
    acc.x += fmaf(eb.x, softplus_f(rb.x), mb.x);
    acc.y += fmaf(eb.y, softplus_f(rb.y), mb.y);
    acc.z += fmaf(eb.z, softplus_f(rb.z), mb.z);
    acc.w += fmaf(eb.w, softplus_f(rb.w), mb.w);
    *(f4*)(out + (size_t)b * OUTT + o) = acc;
}

extern "C" void kernel_launch(void* const* d_in, const int* in_sizes, int n_in,
                              void* d_out, int out_size, void* d_ws, size_t ws_size,
                              hipStream_t stream) {
    const float* x        = (const float*)d_in[0];
    const float* mu       = (const float*)d_in[1];
    const float* ro       = (const float*)d_in[2];
    const float* mu_bias  = (const float*)d_in[3];
    const float* ro_bias  = (const float*)d_in[4];
    const float* eps      = (const float*)d_in[5];
    const float* eps_bias = (const float*)d_in[6];
    float* out = (float*)d_out;

    const size_t part_elems = (size_t)BB * ICH * OUTT;   // 4M floats = 16 MB
    const size_t need = part_elems * sizeof(float);

    if (ws_size >= need) {
        float* part = (float*)d_ws;

        dim3 grid(ICH, BB / B_T);   // 64 x 16 = 1024 blocks, 4 blocks/CU
        bayes_main<<<grid, 256, 0, stream>>>(x, mu, ro, eps, part);
        bayes_reduce<<<(BB * OUTT / 4) / 256, 256, 0, stream>>>(
            part, mu_bias, ro_bias, eps_bias, out);
    } else {
        bayes_mono<<<BB, 256, 0, stream>>>(x, mu, ro, mu_bias, ro_bias,
                                           eps, eps_bias, out);
    }
}

// Round 7
// 369.929 us; speedup vs baseline: 1.0616x; 1.0429x over previous
//
#include <hip/hip_runtime.h>

// BayesianLayer: out[b,o] = sum_i x[b,i]*(eps[b,i,o]*softplus(ro[i,o]) + mu[i,o])
//                          + eps_bias[b,o]*softplus(ro_bias[o]) + mu_bias[o]
// B=64, IN=1024, OUT=1024, fp32. Memory-bound on eps (256 MB, read-once).
//
// R7 = VERBATIM reproduction of R2 (the 368.9 µs champion) to test whether
// its 17 µs edge over the R3-R6 family (385.8-392.7) is real or noise.
// R2 ingredients: 3-kernel pipeline (sig precompute / main ICH=32 B_T=4
// il-outer b-inner / reduce), nt loads on eps, 8 MB part.
//   A: sig[i,o]    = softplus(ro[i,o])                  -> ws[0 .. 1M)
//   B: part[b,c,o] = sum_{i in chunk c} x*(eps*sig+mu)  -> ws[1M .. 3M)
//   C: out[b,o]    = sum_c part + eps_bias*softplus(ro_bias) + mu_bias

#define BB   64
#define INN  1024
#define OUTT 1024
#define B_T  4               // batch rows per main block (sig/mu reuse)
#define ICH  32              // split-K chunks over IN
#define I_C  (INN / ICH)     // 32 i's per main block

typedef float f4 __attribute__((ext_vector_type(4)));

__device__ __forceinline__ float softplus_f(float v) {
    return fmaxf(v, 0.0f) + log1pf(__expf(-fabsf(v)));
}

// ---- kernel A: sig = softplus(ro), 1M elements as 256K float4 ----
__global__ __launch_bounds__(256) void bayes_sig(
    const float* __restrict__ ro, float* __restrict__ sig)
{
    const int g = blockIdx.x * 256 + threadIdx.x;      // float4 index
    const f4 r = *(const f4*)(ro + (size_t)g * 4);
    f4 s;
    s.x = softplus_f(r.x); s.y = softplus_f(r.y);
    s.z = softplus_f(r.z); s.w = softplus_f(r.w);
    *(f4*)(sig + (size_t)g * 4) = s;
}

// ---- kernel B: split-K partials ----
__global__ __launch_bounds__(256) void bayes_main(
    const float* __restrict__ x,        // [B, IN]
    const float* __restrict__ mu,       // [IN, OUT]
    const float* __restrict__ sig,      // [IN, OUT] (precomputed softplus)
    const float* __restrict__ eps,      // [B, IN, OUT]
    float* __restrict__ part)           // [B, ICH, OUT]
{
    __shared__ float xs[B_T][I_C];

    const int t  = threadIdx.x;
    const int o  = t << 2;
    const int c  = blockIdx.x;          // chunk
    const int b0 = blockIdx.y * B_T;
    const int i0 = c * I_C;

    if (t < B_T * I_C) {
        const int b  = t / I_C;
        const int il = t % I_C;
        xs[b][il] = x[(b0 + b) * INN + i0 + il];
    }
    __syncthreads();

    f4 acc[B_T];
#pragma unroll
    for (int b = 0; b < B_T; ++b) acc[b] = (f4)0.0f;

#pragma unroll 4
    for (int il = 0; il < I_C; ++il) {
        const int i = i0 + il;
        const f4 sg4 = *(const f4*)(sig + (size_t)i * OUTT + o);
        const f4 mu4 = *(const f4*)(mu  + (size_t)i * OUTT + o);
#pragma unroll
        for (int b = 0; b < B_T; ++b) {
            const float xb = xs[b][il];
            const f4 e = __builtin_nontemporal_load(
                (const f4*)(eps + ((size_t)(b0 + b) * INN + i) * OUTT + o));
            acc[b].x = fmaf(xb, fmaf(e.x, sg4.x, mu4.x), acc[b].x);
            acc[b].y = fmaf(xb, fmaf(e.y, sg4.y, mu4.y), acc[b].y);
            acc[b].z = fmaf(xb, fmaf(e.z, sg4.z, mu4.z), acc[b].z);
            acc[b].w = fmaf(xb, fmaf(e.w, sg4.w, mu4.w), acc[b].w);
        }
    }

#pragma unroll
    for (int b = 0; b < B_T; ++b) {
        *(f4*)(part + ((size_t)(b0 + b) * ICH + c) * OUTT + o) = acc[b];
    }
}

// ---- kernel C: reduce 32 partials + bias ----
__global__ __launch_bounds__(256) void bayes_reduce(
    const float* __restrict__ part,     // [B, ICH, OUT]
    const float* __restrict__ mu_bias,  // [OUT]
    const float* __restrict__ ro_bias,  // [OUT]
    const float* __restrict__ eps_bias, // [B, OUT]
    float* __restrict__ out)            // [B, OUT]
{
    const int g  = blockIdx.x * 256 + threadIdx.x;   // float4 index over [B*OUT/4]
    const int b  = g >> 8;                           // 256 float4 per row
    const int o  = (g & 255) << 2;

    f4 s = (f4)0.0f;
#pragma unroll
    for (int c = 0; c < ICH; ++c) {
        const f4 p = *(const f4*)(part + ((size_t)b * ICH + c) * OUTT + o);
        s.x += p.x; s.y += p.y; s.z += p.z; s.w += p.w;
    }

    const f4 rb = *(const f4*)(ro_bias + o);
    const f4 mb = *(const f4*)(mu_bias + o);
    const f4 eb = *(const f4*)(eps_bias + (size_t)b * OUTT + o);
    s.x += fmaf(eb.x, softplus_f(rb.x), mb.x);
    s.y += fmaf(eb.y, softplus_f(rb.y), mb.y);
    s.z += fmaf(eb.z, softplus_f(rb.z), mb.z);
    s.w += fmaf(eb.w, softplus_f(rb.w), mb.w);

    *(f4*)(out + (size_t)g * 4) = s;
}

// ---- fallback (ws too small): single deterministic kernel, no scratch ----
__global__ __launch_bounds__(256) void bayes_mono(
    const float* __restrict__ x, const float* __restrict__ mu,
    const float* __restrict__ ro, const float* __restrict__ mu_bias,
    const float* __restrict__ ro_bias, const float* __restrict__ eps,
    const float* __restrict__ eps_bias, float* __restrict__ out)
{
    const int t = threadIdx.x;
    const int o = t << 2;
    const int b = blockIdx.x;

    f4 acc = (f4)0.0f;
    for (int i = 0; i < INN; ++i) {
        const float xb = x[b * INN + i];
        const f4 r4 = *(const f4*)(ro + (size_t)i * OUTT + o);
        const f4 m4 = *(const f4*)(mu + (size_t)i * OUTT + o);
        const f4 e  = *(const f4*)(eps + ((size_t)b * INN + i) * OUTT + o);
        acc.x = fmaf(xb, fmaf(e.x, softplus_f(r4.x), m4.x), acc.x);
        acc.y = fmaf(xb, fmaf(e.y, softplus_f(r4.y), m4.y), acc.y);
        acc.z = fmaf(xb, fmaf(e.z, softplus_f(r4.z), m4.z), acc.z);
        acc.w = fmaf(xb, fmaf(e.w, softplus_f(r4.w), m4.w), acc.w);
    }
    const f4 rb = *(const f4*)(ro_bias + o);
    const f4 mb = *(const f4*)(mu_bias + o);
    const f4 eb = *(const f4*)(eps_bias + (size_t)b * OUTT + o);
    acc.x += fmaf(eb.x, softplus_f(rb.x), mb.x);
    acc.y += fmaf(eb.y, softplus_f(rb.y), mb.y);
    acc.z += fmaf(eb.z, softplus_f(rb.z), mb.z);
    acc.w += fmaf(eb.w, softplus_f(rb.w), mb.w);
    *(f4*)(out + (size_t)b * OUTT + o) = acc;
}

extern "C" void kernel_launch(void* const* d_in, const int* in_sizes, int n_in,
                              void* d_out, int out_size, void* d_ws, size_t ws_size,
                              hipStream_t stream) {
    const float* x        = (const float*)d_in[0];
    const float* mu       = (const float*)d_in[1];
    const float* ro       = (const float*)d_in[2];
    const float* mu_bias  = (const float*)d_in[3];
    const float* ro_bias  = (const float*)d_in[4];
    const float* eps      = (const float*)d_in[5];
    const float* eps_bias = (const float*)d_in[6];
    float* out = (float*)d_out;

    const size_t sig_elems  = (size_t)INN * OUTT;        // 1M floats
    const size_t part_elems = (size_t)BB * ICH * OUTT;   // 2M floats
    const size_t need = (sig_elems + part_elems) * sizeof(float);  // 12 MB

    if (ws_size >= need) {
        float* sig  = (float*)d_ws;
        float* part = sig + sig_elems;

        bayes_sig<<<sig_elems / 1024, 256, 0, stream>>>(ro, sig);
        dim3 grid(ICH, BB / B_T);   // 32 x 16 = 512 blocks, 2 blocks/CU
        bayes_main<<<grid, 256, 0, stream>>>(x, mu, sig, eps, part);
        bayes_reduce<<<(BB * OUTT / 4) / 256, 256, 0, stream>>>(
            part, mu_bias, ro_bias, eps_bias, out);
    } else {
        bayes_mono<<<BB, 256, 0, stream>>>(x, mu, ro, mu_bias, ro_bias,
                                           eps, eps_bias, out);
    }
}